// Round 1
// baseline (1240.212 us; speedup 1.0000x reference)
//
#include <hip/hip_runtime.h>

#define D_FEAT 64
constexpr float SLOPE = 0.01f;
constexpr float EPS_N = 1e-6f;

__device__ __forceinline__ float lrelu(float v) { return v >= 0.f ? v : SLOPE * v; }

// ---------------------------------------------------------------------------
// Stage 1: h = (leaky_relu(leaky_relu(x + states@Ws^T) @ W1^T)) @ W2^T
// 64 threads (one wave) per node; 4 nodes per 256-thread block iteration.
// W matrices in LDS with +1 padding: lane j reads W[j*65+k] -> bank (j+k)%32,
// 2-way aliasing = free (m136).
// ---------------------------------------------------------------------------
__global__ __launch_bounds__(256) void mlp_kernel(
    const float* __restrict__ x, const float* __restrict__ states,
    const float* __restrict__ Ws, const float* __restrict__ W1,
    const float* __restrict__ W2, float* __restrict__ h, int n_nodes)
{
    __shared__ float sWs[D_FEAT * 65];
    __shared__ float sW1[D_FEAT * 65];
    __shared__ float sW2[D_FEAT * 65];
    __shared__ float4 sbufA[4][16];
    __shared__ float4 sbufB[4][16];
    float* sA = (float*)sbufA;
    float* sB = (float*)sbufB;

    const int t = threadIdx.x;
    for (int i = t; i < D_FEAT * D_FEAT; i += 256) {
        int j = i >> 6, k = i & 63;
        sWs[j * 65 + k] = Ws[i];
        sW1[j * 65 + k] = W1[i];
        sW2[j * 65 + k] = W2[i];
    }
    __syncthreads();

    const int grp = t >> 6;       // 0..3  (node slot within block)
    const int j   = t & 63;       // output channel
    const int jw  = j * 65;

    for (int n0 = blockIdx.x * 4; n0 < n_nodes; n0 += gridDim.x * 4) {
        const int n = n0 + grp;
        float sv = 0.f, xv = 0.f;
        if (n < n_nodes) {
            sv = states[(size_t)n * D_FEAT + j];
            xv = x[(size_t)n * D_FEAT + j];
        }
        sA[grp * 64 + j] = sv;
        __syncthreads();

        // stage 1: h2 = lrelu(x + states @ Ws^T)
        float acc = xv;
        #pragma unroll
        for (int k = 0; k < D_FEAT; k += 4) {
            float4 s4 = sbufA[grp][k >> 2];   // broadcast within wave
            acc += s4.x * sWs[jw + k]     + s4.y * sWs[jw + k + 1]
                 + s4.z * sWs[jw + k + 2] + s4.w * sWs[jw + k + 3];
        }
        acc = lrelu(acc);
        sB[grp * 64 + j] = acc;
        __syncthreads();

        // stage 2: h3 = lrelu(h2 @ W1^T)
        float acc2 = 0.f;
        #pragma unroll
        for (int k = 0; k < D_FEAT; k += 4) {
            float4 s4 = sbufB[grp][k >> 2];
            acc2 += s4.x * sW1[jw + k]     + s4.y * sW1[jw + k + 1]
                  + s4.z * sW1[jw + k + 2] + s4.w * sW1[jw + k + 3];
        }
        acc2 = lrelu(acc2);
        sA[grp * 64 + j] = acc2;   // stage-1 reads of sA all done (barrier above)
        __syncthreads();

        // stage 3: h = h3 @ W2^T
        float acc3 = 0.f;
        #pragma unroll
        for (int k = 0; k < D_FEAT; k += 4) {
            float4 s4 = sbufA[grp][k >> 2];
            acc3 += s4.x * sW2[jw + k]     + s4.y * sW2[jw + k + 1]
                  + s4.z * sW2[jw + k + 2] + s4.w * sW2[jw + k + 3];
        }
        if (n < n_nodes) h[(size_t)n * D_FEAT + j] = acc3;
        __syncthreads();   // protect sA before next iteration's overwrite
    }
}

// ---------------------------------------------------------------------------
// Stage 2: scatter-add  agg[dst] += w[e] * h[src]   (16 threads per edge)
// ---------------------------------------------------------------------------
__global__ __launch_bounds__(256) void scatter_kernel(
    const int* __restrict__ eidx, const float* __restrict__ w,
    const float* __restrict__ h, float* __restrict__ agg, int n_edges)
{
    long long t = (long long)blockIdx.x * blockDim.x + threadIdx.x;
    int e = (int)(t >> 4);
    if (e >= n_edges) return;
    int c = ((int)t & 15) * 4;

    int dst = eidx[e];             // edge_index[0]
    int src = eidx[n_edges + e];   // edge_index[1]
    float wv = w[e];

    const float4 hv = *reinterpret_cast<const float4*>(h + (size_t)src * D_FEAT + c);
    float* p = agg + (size_t)dst * D_FEAT + c;
    unsafeAtomicAdd(p + 0, wv * hv.x);
    unsafeAtomicAdd(p + 1, wv * hv.y);
    unsafeAtomicAdd(p + 2, wv * hv.z);
    unsafeAtomicAdd(p + 3, wv * hv.w);
}

// ---------------------------------------------------------------------------
// Stage 3: GraphNorm, in place on agg (= d_out). One block per graph.
// batch is sorted with equal-size segments (npg nodes each) per setup.
// ---------------------------------------------------------------------------
__global__ __launch_bounds__(256) void norm_kernel(
    float* __restrict__ io, const float* __restrict__ gamma,
    const float* __restrict__ beta, int npg)
{
    const int g = blockIdx.x;
    const int t = threadIdx.x;
    const int j = t & 63;
    const int r = t >> 6;
    const size_t base = (size_t)g * npg * D_FEAT;

    float sum = 0.f, sq = 0.f;
    for (int n = r; n < npg; n += 4) {
        float v = io[base + (size_t)n * D_FEAT + j];
        sum += v; sq += v * v;
    }

    __shared__ float s_red[2][4][64];
    s_red[0][r][j] = sum;
    s_red[1][r][j] = sq;
    __syncthreads();

    __shared__ float s_mu[64], s_scale[64], s_beta[64];
    if (r == 0) {
        float S = s_red[0][0][j] + s_red[0][1][j] + s_red[0][2][j] + s_red[0][3][j];
        float Q = s_red[1][0][j] + s_red[1][1][j] + s_red[1][2][j] + s_red[1][3][j];
        float cnt = (float)npg;
        float mu = S / cnt;
        float var = (Q - cnt * mu * mu) / fmaxf(cnt - 1.f, 1.f);
        var = fmaxf(var, 0.f);
        s_mu[j]    = mu;
        s_scale[j] = gamma[j] / (sqrtf(var) + EPS_N);
        s_beta[j]  = beta[j];
    }
    __syncthreads();

    const float mu = s_mu[j], sc = s_scale[j], be = s_beta[j];
    for (int n = r; n < npg; n += 4) {
        size_t idx = base + (size_t)n * D_FEAT + j;
        io[idx] = (io[idx] - mu) * sc + be;
    }
}

extern "C" void kernel_launch(void* const* d_in, const int* in_sizes, int n_in,
                              void* d_out, int out_size, void* d_ws, size_t ws_size,
                              hipStream_t stream)
{
    const float* x      = (const float*)d_in[0];
    const float* states = (const float*)d_in[1];
    const int*   eidx   = (const int*)d_in[2];
    const float* w      = (const float*)d_in[3];
    // d_in[4] = batch, d_in[5] = batch_num: sorted equal segments per setup
    const float* Ws     = (const float*)d_in[6];
    const float* W1     = (const float*)d_in[7];
    const float* W2     = (const float*)d_in[8];
    const float* gamma  = (const float*)d_in[9];
    const float* beta   = (const float*)d_in[10];

    const int n_nodes  = in_sizes[0] / D_FEAT;
    const int n_edges  = in_sizes[3];
    const int n_graphs = in_sizes[5];
    const int npg      = n_nodes / n_graphs;

    float* h   = (float*)d_ws;     // [n_nodes, 64] f32 = 25.6 MB
    float* agg = (float*)d_out;    // accumulate in d_out, normalize in place

    hipMemsetAsync(agg, 0, (size_t)n_nodes * D_FEAT * sizeof(float), stream);
    mlp_kernel<<<768, 256, 0, stream>>>(x, states, Ws, W1, W2, h, n_nodes);

    long long sthreads = (long long)n_edges * 16;
    int sblocks = (int)((sthreads + 255) / 256);
    scatter_kernel<<<sblocks, 256, 0, stream>>>(eidx, w, h, agg, n_edges);

    norm_kernel<<<n_graphs, 256, 0, stream>>>(agg, gamma, beta, npg);
}

// Round 3
// 440.025 us; speedup vs baseline: 2.8185x; 2.8185x over previous
//
#include <hip/hip_runtime.h>

#define D_FEAT 64
constexpr float SLOPE = 0.01f;
constexpr float EPS_N = 1e-6f;
constexpr int SCAN_CHUNK = 2048;   // elements per scan block (256 thr x 8)

__device__ __forceinline__ float lrelu(float v) { return v >= 0.f ? v : SLOPE * v; }

// ---------------------------------------------------------------------------
// Stage 1: h = (leaky_relu(leaky_relu(x + states@Ws^T) @ W1^T)) @ W2^T
// ---------------------------------------------------------------------------
__global__ __launch_bounds__(256) void mlp_kernel(
    const float* __restrict__ x, const float* __restrict__ states,
    const float* __restrict__ Ws, const float* __restrict__ W1,
    const float* __restrict__ W2, float* __restrict__ h, int n_nodes)
{
    __shared__ float sWs[D_FEAT * 65];
    __shared__ float sW1[D_FEAT * 65];
    __shared__ float sW2[D_FEAT * 65];
    __shared__ float4 sbufA[4][16];
    __shared__ float4 sbufB[4][16];
    float* sA = (float*)sbufA;
    float* sB = (float*)sbufB;

    const int t = threadIdx.x;
    for (int i = t; i < D_FEAT * D_FEAT; i += 256) {
        int j = i >> 6, k = i & 63;
        sWs[j * 65 + k] = Ws[i];
        sW1[j * 65 + k] = W1[i];
        sW2[j * 65 + k] = W2[i];
    }
    __syncthreads();

    const int grp = t >> 6;
    const int j   = t & 63;
    const int jw  = j * 65;

    for (int n0 = blockIdx.x * 4; n0 < n_nodes; n0 += gridDim.x * 4) {
        const int n = n0 + grp;
        float sv = 0.f, xv = 0.f;
        if (n < n_nodes) {
            sv = states[(size_t)n * D_FEAT + j];
            xv = x[(size_t)n * D_FEAT + j];
        }
        sA[grp * 64 + j] = sv;
        __syncthreads();

        float acc = xv;
        #pragma unroll
        for (int k = 0; k < D_FEAT; k += 4) {
            float4 s4 = sbufA[grp][k >> 2];
            acc += s4.x * sWs[jw + k]     + s4.y * sWs[jw + k + 1]
                 + s4.z * sWs[jw + k + 2] + s4.w * sWs[jw + k + 3];
        }
        acc = lrelu(acc);
        sB[grp * 64 + j] = acc;
        __syncthreads();

        float acc2 = 0.f;
        #pragma unroll
        for (int k = 0; k < D_FEAT; k += 4) {
            float4 s4 = sbufB[grp][k >> 2];
            acc2 += s4.x * sW1[jw + k]     + s4.y * sW1[jw + k + 1]
                  + s4.z * sW1[jw + k + 2] + s4.w * sW1[jw + k + 3];
        }
        acc2 = lrelu(acc2);
        sA[grp * 64 + j] = acc2;
        __syncthreads();

        float acc3 = 0.f;
        #pragma unroll
        for (int k = 0; k < D_FEAT; k += 4) {
            float4 s4 = sbufA[grp][k >> 2];
            acc3 += s4.x * sW2[jw + k]     + s4.y * sW2[jw + k + 1]
                  + s4.z * sW2[jw + k + 2] + s4.w * sW2[jw + k + 3];
        }
        if (n < n_nodes) h[(size_t)n * D_FEAT + j] = acc3;
        __syncthreads();
    }
}

// ---------------------------------------------------------------------------
// CSR build: histogram -> scan -> scatter records sorted by destination
// ---------------------------------------------------------------------------
__global__ __launch_bounds__(256) void hist_kernel(
    const int* __restrict__ eidx, int* __restrict__ counts, int n_edges)
{
    for (int e = blockIdx.x * blockDim.x + threadIdx.x; e < n_edges;
         e += gridDim.x * blockDim.x)
        atomicAdd(&counts[eidx[e]], 1);           // dst = eidx[0][e]
}

__global__ __launch_bounds__(256) void scan1_kernel(
    const int* __restrict__ counts, int* __restrict__ row_start,
    int* __restrict__ partials, int n)
{
    __shared__ int s[256];
    const int b = blockIdx.x, t = threadIdx.x;
    const int base = b * SCAN_CHUNK + t * 8;
    int v[8]; int sum = 0;
    #pragma unroll
    for (int i = 0; i < 8; ++i) {
        v[i] = (base + i < n) ? counts[base + i] : 0;
        sum += v[i];
    }
    s[t] = sum;
    __syncthreads();
    for (int off = 1; off < 256; off <<= 1) {
        int y = (t >= off) ? s[t - off] : 0;
        __syncthreads();
        s[t] += y;
        __syncthreads();
    }
    int excl = s[t] - sum;    // exclusive prefix within chunk
    #pragma unroll
    for (int i = 0; i < 8; ++i) {
        if (base + i < n) row_start[base + i] = excl;
        excl += v[i];
    }
    if (t == 255) partials[b] = s[255];
}

__global__ __launch_bounds__(256) void scan2_kernel(int* partials, int nchunks)
{
    __shared__ int s[256];
    const int t = threadIdx.x;
    int v = (t < nchunks) ? partials[t] : 0;
    s[t] = v;
    __syncthreads();
    for (int off = 1; off < 256; off <<= 1) {
        int y = (t >= off) ? s[t - off] : 0;
        __syncthreads();
        s[t] += y;
        __syncthreads();
    }
    if (t < nchunks) partials[t] = s[t] - v;      // exclusive
}

__global__ __launch_bounds__(256) void scan3_kernel(
    int* __restrict__ row_start, int* __restrict__ cursor,
    const int* __restrict__ partials, int n, int n_edges)
{
    int i = blockIdx.x * blockDim.x + threadIdx.x;
    if (i == 0) row_start[n] = n_edges;
    for (; i < n; i += gridDim.x * blockDim.x) {
        int v = row_start[i] + partials[i / SCAN_CHUNK];
        row_start[i] = v;
        cursor[i]    = v;
    }
}

__global__ __launch_bounds__(256) void scatter_build_kernel(
    const int* __restrict__ eidx, const float* __restrict__ w,
    int* __restrict__ cursor, int2* __restrict__ rec, int n_edges)
{
    for (int e = blockIdx.x * blockDim.x + threadIdx.x; e < n_edges;
         e += gridDim.x * blockDim.x) {
        int dst = eidx[e];
        int src = eidx[n_edges + e];
        float wv = w[e];
        int pos = atomicAdd(&cursor[dst], 1);
        rec[pos] = make_int2(src, __float_as_int(wv));
    }
}

// ---------------------------------------------------------------------------
// Gather-accumulate: one wave per destination node, lane = channel.
// No atomics; one coalesced 256B h-row read per edge.
// ---------------------------------------------------------------------------
__global__ __launch_bounds__(256) void gather_kernel(
    const int* __restrict__ row_start, const int2* __restrict__ rec,
    const float* __restrict__ h, float* __restrict__ agg, int n_nodes)
{
    const int wave = threadIdx.x >> 6;
    const int lane = threadIdx.x & 63;
    const int node = blockIdx.x * 4 + wave;
    if (node >= n_nodes) return;

    const int start = row_start[node];
    const int end   = row_start[node + 1];

    float acc = 0.f;
    int i = start;
    for (; i + 1 < end; i += 2) {
        int2 r0 = rec[i];
        int2 r1 = rec[i + 1];
        float h0 = h[(size_t)r0.x * D_FEAT + lane];
        float h1 = h[(size_t)r1.x * D_FEAT + lane];
        acc += __int_as_float(r0.y) * h0;
        acc += __int_as_float(r1.y) * h1;
    }
    if (i < end) {
        int2 r0 = rec[i];
        acc += __int_as_float(r0.y) * h[(size_t)r0.x * D_FEAT + lane];
    }
    agg[(size_t)node * D_FEAT + lane] = acc;
}

// ---------------------------------------------------------------------------
// Fallback scatter (atomics) if workspace is too small for CSR build
// ---------------------------------------------------------------------------
__global__ __launch_bounds__(256) void scatter_atomic_kernel(
    const int* __restrict__ eidx, const float* __restrict__ w,
    const float* __restrict__ h, float* __restrict__ agg, int n_edges)
{
    long long t = (long long)blockIdx.x * blockDim.x + threadIdx.x;
    int e = (int)(t >> 4);
    if (e >= n_edges) return;
    int c = ((int)t & 15) * 4;
    int dst = eidx[e];
    int src = eidx[n_edges + e];
    float wv = w[e];
    const float4 hv = *reinterpret_cast<const float4*>(h + (size_t)src * D_FEAT + c);
    float* p = agg + (size_t)dst * D_FEAT + c;
    unsafeAtomicAdd(p + 0, wv * hv.x);
    unsafeAtomicAdd(p + 1, wv * hv.y);
    unsafeAtomicAdd(p + 2, wv * hv.z);
    unsafeAtomicAdd(p + 3, wv * hv.w);
}

// ---------------------------------------------------------------------------
// Stage 3: GraphNorm in place on d_out
// ---------------------------------------------------------------------------
__global__ __launch_bounds__(256) void norm_kernel(
    float* __restrict__ io, const float* __restrict__ gamma,
    const float* __restrict__ beta, int npg)
{
    const int g = blockIdx.x;
    const int t = threadIdx.x;
    const int j = t & 63;
    const int r = t >> 6;
    const size_t base = (size_t)g * npg * D_FEAT;

    float sum = 0.f, sq = 0.f;
    for (int n = r; n < npg; n += 4) {
        float v = io[base + (size_t)n * D_FEAT + j];
        sum += v; sq += v * v;
    }

    __shared__ float s_red[2][4][64];
    s_red[0][r][j] = sum;
    s_red[1][r][j] = sq;
    __syncthreads();

    __shared__ float s_mu[64], s_scale[64], s_beta[64];
    if (r == 0) {
        float S = s_red[0][0][j] + s_red[0][1][j] + s_red[0][2][j] + s_red[0][3][j];
        float Q = s_red[1][0][j] + s_red[1][1][j] + s_red[1][2][j] + s_red[1][3][j];
        float cnt = (float)npg;
        float mu = S / cnt;
        float var = (Q - cnt * mu * mu) / fmaxf(cnt - 1.f, 1.f);
        var = fmaxf(var, 0.f);
        s_mu[j]    = mu;
        s_scale[j] = gamma[j] / (sqrtf(var) + EPS_N);
        s_beta[j]  = beta[j];
    }
    __syncthreads();

    const float mu = s_mu[j], sc = s_scale[j], be = s_beta[j];
    for (int n = r; n < npg; n += 4) {
        size_t idx = base + (size_t)n * D_FEAT + j;
        io[idx] = (io[idx] - mu) * sc + be;
    }
}

extern "C" void kernel_launch(void* const* d_in, const int* in_sizes, int n_in,
                              void* d_out, int out_size, void* d_ws, size_t ws_size,
                              hipStream_t stream)
{
    const float* x      = (const float*)d_in[0];
    const float* states = (const float*)d_in[1];
    const int*   eidx   = (const int*)d_in[2];
    const float* w      = (const float*)d_in[3];
    const float* Ws     = (const float*)d_in[6];
    const float* W1     = (const float*)d_in[7];
    const float* W2     = (const float*)d_in[8];
    const float* gamma  = (const float*)d_in[9];
    const float* beta   = (const float*)d_in[10];

    const int n_nodes  = in_sizes[0] / D_FEAT;
    const int n_edges  = in_sizes[3];
    const int n_graphs = in_sizes[5];
    const int npg      = n_nodes / n_graphs;

    // workspace layout
    char* ws = (char*)d_ws;
    size_t hBytes    = (size_t)n_nodes * D_FEAT * sizeof(float);       // 25.6 MB
    size_t recBytes  = (size_t)n_edges * sizeof(int2);                 // 9.6 MB
    size_t rsBytes   = (size_t)(n_nodes + 1) * sizeof(int);
    size_t curBytes  = (size_t)n_nodes * sizeof(int);
    size_t partBytes = 256 * sizeof(int);
    size_t need = hBytes + recBytes + rsBytes + curBytes + partBytes;

    float* h = (float*)ws;
    float* agg = (float*)d_out;

    mlp_kernel<<<768, 256, 0, stream>>>(x, states, Ws, W1, W2, h, n_nodes);

    if (ws_size >= need) {
        int2* rec      = (int2*)(ws + hBytes);
        int*  row_start= (int*)(ws + hBytes + recBytes);
        int*  cursor   = (int*)(ws + hBytes + recBytes + rsBytes);
        int*  partials = (int*)(ws + hBytes + recBytes + rsBytes + curBytes);
        int*  counts   = cursor;   // reuse: counts consumed by scan before cursor written

        hipMemsetAsync(counts, 0, (size_t)n_nodes * sizeof(int), stream);
        hist_kernel<<<1024, 256, 0, stream>>>(eidx, counts, n_edges);

        int nchunks = (n_nodes + SCAN_CHUNK - 1) / SCAN_CHUNK;   // 49 for 100k
        scan1_kernel<<<nchunks, 256, 0, stream>>>(counts, row_start, partials, n_nodes);
        scan2_kernel<<<1, 256, 0, stream>>>(partials, nchunks);
        scan3_kernel<<<256, 256, 0, stream>>>(row_start, cursor, partials, n_nodes, n_edges);

        scatter_build_kernel<<<1024, 256, 0, stream>>>(eidx, w, cursor, rec, n_edges);

        gather_kernel<<<(n_nodes + 3) / 4, 256, 0, stream>>>(row_start, rec, h, agg, n_nodes);
    } else {
        hipMemsetAsync(agg, 0, hBytes, stream);
        long long sthreads = (long long)n_edges * 16;
        int sblocks = (int)((sthreads + 255) / 256);
        scatter_atomic_kernel<<<sblocks, 256, 0, stream>>>(eidx, w, h, agg, n_edges);
    }

    norm_kernel<<<n_graphs, 256, 0, stream>>>(agg, gamma, beta, npg);
}

// Round 6
// 370.476 us; speedup vs baseline: 3.3476x; 1.1877x over previous
//
#include <hip/hip_runtime.h>

#define D_FEAT 64
constexpr float SLOPE = 0.01f;
constexpr float EPS_N = 1e-6f;
constexpr int SCAN_CHUNK = 2048;   // elements per scan block (256 thr x 8)
constexpr int LDT = 66;            // LDS row stride (pad 64 -> 66)

__device__ __forceinline__ float lrelu(float v) { return v >= 0.f ? v : SLOPE * v; }

// ---------------------------------------------------------------------------
// Stage 1: h = (leaky_relu(leaky_relu(x + states@Ws^T) @ W1^T)) @ W2^T
// Register-tiled f32 GEMM: block = 64-node tile, thread = 4 nodes x 4 ch.
// W_t[k][c] = W[c][k]; S_t/H_t[k][n] = act[n][k]. Inner loop per k:
// 2x ds_read_b128 + 16 independent FMAs.
// ---------------------------------------------------------------------------
__global__ __launch_bounds__(256, 3) void mlp_kernel(
    const float* __restrict__ x, const float* __restrict__ states,
    const float* __restrict__ Ws, const float* __restrict__ W1,
    const float* __restrict__ W2, float* __restrict__ h, int n_nodes)
{
    __shared__ float S_t[D_FEAT * LDT];
    __shared__ float H_t[D_FEAT * LDT];
    __shared__ float W_t[D_FEAT * LDT];

    const int t  = threadIdx.x;
    const int tn = t & 15;          // node group (4 nodes)
    const int tc = t >> 4;          // channel group (4 ch)
    const int nb = blockIdx.x * 64; // tile base node

    // ---- stage weights transposed: each thread covers 4 of 16 segments ----
    // (BUGFIX vs R4: previous version staged only segments 0..3 -> k=16..63 garbage)
#define STAGE_W(Wp)                                                          \
    {                                                                        \
        const int wrow = t >> 2;                                             \
        _Pragma("unroll")                                                    \
        for (int s = (t & 3); s < 16; s += 4) {                              \
            float4 wv = *reinterpret_cast<const float4*>((Wp) + wrow * 64 + s * 4); \
            W_t[(s * 4 + 0) * LDT + wrow] = wv.x;                            \
            W_t[(s * 4 + 1) * LDT + wrow] = wv.y;                            \
            W_t[(s * 4 + 2) * LDT + wrow] = wv.z;                            \
            W_t[(s * 4 + 3) * LDT + wrow] = wv.w;                            \
        }                                                                    \
    }

    STAGE_W(Ws);
    // ---- stage states tile transposed: S_t[k][n] ----
    {
        const int r = t >> 4, kg = t & 15;       // row-in-tile base r, k-group kg
        #pragma unroll
        for (int i = 0; i < 4; ++i) {
            int nloc = r + i * 16;
            int node = nb + nloc;
            float4 sv = make_float4(0.f, 0.f, 0.f, 0.f);
            if (node < n_nodes)
                sv = *reinterpret_cast<const float4*>(states + (size_t)node * D_FEAT + kg * 4);
            S_t[(kg * 4 + 0) * LDT + nloc] = sv.x;
            S_t[(kg * 4 + 1) * LDT + nloc] = sv.y;
            S_t[(kg * 4 + 2) * LDT + nloc] = sv.z;
            S_t[(kg * 4 + 3) * LDT + nloc] = sv.w;
        }
    }
    __syncthreads();

    float acc[4][4];

    // ---- stage 1: h2 = lrelu(x + states @ Ws^T) ----
    #pragma unroll
    for (int i = 0; i < 4; ++i) {
        int node = nb + tn * 4 + i;
        if (node < n_nodes) {
            float4 xv = *reinterpret_cast<const float4*>(x + (size_t)node * D_FEAT + tc * 4);
            acc[i][0] = xv.x; acc[i][1] = xv.y; acc[i][2] = xv.z; acc[i][3] = xv.w;
        } else {
            acc[i][0] = acc[i][1] = acc[i][2] = acc[i][3] = 0.f;
        }
    }
    #pragma unroll 8
    for (int k = 0; k < D_FEAT; ++k) {
        float4 a = *reinterpret_cast<const float4*>(&S_t[k * LDT + tn * 4]);
        float4 b = *reinterpret_cast<const float4*>(&W_t[k * LDT + tc * 4]);
        const float av[4] = {a.x, a.y, a.z, a.w};
        const float bv[4] = {b.x, b.y, b.z, b.w};
        #pragma unroll
        for (int i = 0; i < 4; ++i)
            #pragma unroll
            for (int j = 0; j < 4; ++j)
                acc[i][j] += av[i] * bv[j];
    }
    #pragma unroll
    for (int i = 0; i < 4; ++i)
        #pragma unroll
        for (int j = 0; j < 4; ++j)
            H_t[(tc * 4 + j) * LDT + tn * 4 + i] = lrelu(acc[i][j]);
    __syncthreads();

    // ---- reload W1 ----
    STAGE_W(W1);
    __syncthreads();

    // ---- stage 2: h3 = lrelu(h2 @ W1^T) ----
    #pragma unroll
    for (int i = 0; i < 4; ++i)
        #pragma unroll
        for (int j = 0; j < 4; ++j)
            acc[i][j] = 0.f;
    #pragma unroll 8
    for (int k = 0; k < D_FEAT; ++k) {
        float4 a = *reinterpret_cast<const float4*>(&H_t[k * LDT + tn * 4]);
        float4 b = *reinterpret_cast<const float4*>(&W_t[k * LDT + tc * 4]);
        const float av[4] = {a.x, a.y, a.z, a.w};
        const float bv[4] = {b.x, b.y, b.z, b.w};
        #pragma unroll
        for (int i = 0; i < 4; ++i)
            #pragma unroll
            for (int j = 0; j < 4; ++j)
                acc[i][j] += av[i] * bv[j];
    }
    #pragma unroll
    for (int i = 0; i < 4; ++i)
        #pragma unroll
        for (int j = 0; j < 4; ++j)
            S_t[(tc * 4 + j) * LDT + tn * 4 + i] = lrelu(acc[i][j]);  // h3 overwrites S_t
    __syncthreads();

    // ---- reload W2 ----
    STAGE_W(W2);
    __syncthreads();

    // ---- stage 3: h = h3 @ W2^T ----
    #pragma unroll
    for (int i = 0; i < 4; ++i)
        #pragma unroll
        for (int j = 0; j < 4; ++j)
            acc[i][j] = 0.f;
    #pragma unroll 8
    for (int k = 0; k < D_FEAT; ++k) {
        float4 a = *reinterpret_cast<const float4*>(&S_t[k * LDT + tn * 4]);
        float4 b = *reinterpret_cast<const float4*>(&W_t[k * LDT + tc * 4]);
        const float av[4] = {a.x, a.y, a.z, a.w};
        const float bv[4] = {b.x, b.y, b.z, b.w};
        #pragma unroll
        for (int i = 0; i < 4; ++i)
            #pragma unroll
            for (int j = 0; j < 4; ++j)
                acc[i][j] += av[i] * bv[j];
    }
    #pragma unroll
    for (int i = 0; i < 4; ++i) {
        int node = nb + tn * 4 + i;
        if (node < n_nodes) {
            float4 o = make_float4(acc[i][0], acc[i][1], acc[i][2], acc[i][3]);
            *reinterpret_cast<float4*>(h + (size_t)node * D_FEAT + tc * 4) = o;
        }
    }
#undef STAGE_W
}

// ---------------------------------------------------------------------------
// CSR build: histogram -> scan -> scatter records sorted by destination
// ---------------------------------------------------------------------------
__global__ __launch_bounds__(256) void hist_kernel(
    const int* __restrict__ eidx, int* __restrict__ counts, int n_edges)
{
    for (int e = blockIdx.x * blockDim.x + threadIdx.x; e < n_edges;
         e += gridDim.x * blockDim.x)
        atomicAdd(&counts[eidx[e]], 1);           // dst = eidx[0][e]
}

__global__ __launch_bounds__(256) void scan1_kernel(
    const int* __restrict__ counts, int* __restrict__ row_start,
    int* __restrict__ partials, int n)
{
    __shared__ int s[256];
    const int b = blockIdx.x, t = threadIdx.x;
    const int base = b * SCAN_CHUNK + t * 8;
    int v[8]; int sum = 0;
    #pragma unroll
    for (int i = 0; i < 8; ++i) {
        v[i] = (base + i < n) ? counts[base + i] : 0;
        sum += v[i];
    }
    s[t] = sum;
    __syncthreads();
    for (int off = 1; off < 256; off <<= 1) {
        int y = (t >= off) ? s[t - off] : 0;
        __syncthreads();
        s[t] += y;
        __syncthreads();
    }
    int excl = s[t] - sum;    // exclusive prefix within chunk
    #pragma unroll
    for (int i = 0; i < 8; ++i) {
        if (base + i < n) row_start[base + i] = excl;
        excl += v[i];
    }
    if (t == 255) partials[b] = s[255];
}

__global__ __launch_bounds__(256) void scan2_kernel(int* partials, int nchunks)
{
    __shared__ int s[256];
    const int t = threadIdx.x;
    int v = (t < nchunks) ? partials[t] : 0;
    s[t] = v;
    __syncthreads();
    for (int off = 1; off < 256; off <<= 1) {
        int y = (t >= off) ? s[t - off] : 0;
        __syncthreads();
        s[t] += y;
        __syncthreads();
    }
    if (t < nchunks) partials[t] = s[t] - v;      // exclusive
}

__global__ __launch_bounds__(256) void scan3_kernel(
    int* __restrict__ row_start, int* __restrict__ cursor,
    const int* __restrict__ partials, int n, int n_edges)
{
    int i = blockIdx.x * blockDim.x + threadIdx.x;
    if (i == 0) row_start[n] = n_edges;
    for (; i < n; i += gridDim.x * blockDim.x) {
        int v = row_start[i] + partials[i / SCAN_CHUNK];
        row_start[i] = v;
        cursor[i]    = v;
    }
}

__global__ __launch_bounds__(256) void scatter_build_kernel(
    const int* __restrict__ eidx, const float* __restrict__ w,
    int* __restrict__ cursor, int2* __restrict__ rec, int n_edges)
{
    for (int e = blockIdx.x * blockDim.x + threadIdx.x; e < n_edges;
         e += gridDim.x * blockDim.x) {
        int dst = eidx[e];
        int src = eidx[n_edges + e];
        float wv = w[e];
        int pos = atomicAdd(&cursor[dst], 1);
        rec[pos] = make_int2(src, __float_as_int(wv));
    }
}

// ---------------------------------------------------------------------------
// Gather-accumulate: one wave per destination node, lane = channel.
// ---------------------------------------------------------------------------
__global__ __launch_bounds__(256) void gather_kernel(
    const int* __restrict__ row_start, const int2* __restrict__ rec,
    const float* __restrict__ h, float* __restrict__ agg, int n_nodes)
{
    const int wave = threadIdx.x >> 6;
    const int lane = threadIdx.x & 63;
    const int node = blockIdx.x * 4 + wave;
    if (node >= n_nodes) return;

    const int start = row_start[node];
    const int end   = row_start[node + 1];

    float acc = 0.f;
    int i = start;
    for (; i + 1 < end; i += 2) {
        int2 r0 = rec[i];
        int2 r1 = rec[i + 1];
        float h0 = h[(size_t)r0.x * D_FEAT + lane];
        float h1 = h[(size_t)r1.x * D_FEAT + lane];
        acc += __int_as_float(r0.y) * h0;
        acc += __int_as_float(r1.y) * h1;
    }
    if (i < end) {
        int2 r0 = rec[i];
        acc += __int_as_float(r0.y) * h[(size_t)r0.x * D_FEAT + lane];
    }
    agg[(size_t)node * D_FEAT + lane] = acc;
}

// ---------------------------------------------------------------------------
// Fallback scatter (atomics) if workspace is too small for CSR build
// ---------------------------------------------------------------------------
__global__ __launch_bounds__(256) void scatter_atomic_kernel(
    const int* __restrict__ eidx, const float* __restrict__ w,
    const float* __restrict__ h, float* __restrict__ agg, int n_edges)
{
    long long t = (long long)blockIdx.x * blockDim.x + threadIdx.x;
    int e = (int)(t >> 4);
    if (e >= n_edges) return;
    int c = ((int)t & 15) * 4;
    int dst = eidx[e];
    int src = eidx[n_edges + e];
    float wv = w[e];
    const float4 hv = *reinterpret_cast<const float4*>(h + (size_t)src * D_FEAT + c);
    float* p = agg + (size_t)dst * D_FEAT + c;
    unsafeAtomicAdd(p + 0, wv * hv.x);
    unsafeAtomicAdd(p + 1, wv * hv.y);
    unsafeAtomicAdd(p + 2, wv * hv.z);
    unsafeAtomicAdd(p + 3, wv * hv.w);
}

// ---------------------------------------------------------------------------
// Stage 3: GraphNorm in place on d_out
// ---------------------------------------------------------------------------
__global__ __launch_bounds__(256) void norm_kernel(
    float* __restrict__ io, const float* __restrict__ gamma,
    const float* __restrict__ beta, int npg)
{
    const int g = blockIdx.x;
    const int t = threadIdx.x;
    const int j = t & 63;
    const int r = t >> 6;
    const size_t base = (size_t)g * npg * D_FEAT;

    float sum = 0.f, sq = 0.f;
    for (int n = r; n < npg; n += 4) {
        float v = io[base + (size_t)n * D_FEAT + j];
        sum += v; sq += v * v;
    }

    __shared__ float s_red[2][4][64];
    s_red[0][r][j] = sum;
    s_red[1][r][j] = sq;
    __syncthreads();

    __shared__ float s_mu[64], s_scale[64], s_beta[64];
    if (r == 0) {
        float S = s_red[0][0][j] + s_red[0][1][j] + s_red[0][2][j] + s_red[0][3][j];
        float Q = s_red[1][0][j] + s_red[1][1][j] + s_red[1][2][j] + s_red[1][3][j];
        float cnt = (float)npg;
        float mu = S / cnt;
        float var = (Q - cnt * mu * mu) / fmaxf(cnt - 1.f, 1.f);
        var = fmaxf(var, 0.f);
        s_mu[j]    = mu;
        s_scale[j] = gamma[j] / (sqrtf(var) + EPS_N);
        s_beta[j]  = beta[j];
    }
    __syncthreads();

    const float mu = s_mu[j], sc = s_scale[j], be = s_beta[j];
    for (int n = r; n < npg; n += 4) {
        size_t idx = base + (size_t)n * D_FEAT + j;
        io[idx] = (io[idx] - mu) * sc + be;
    }
}

extern "C" void kernel_launch(void* const* d_in, const int* in_sizes, int n_in,
                              void* d_out, int out_size, void* d_ws, size_t ws_size,
                              hipStream_t stream)
{
    const float* x      = (const float*)d_in[0];
    const float* states = (const float*)d_in[1];
    const int*   eidx   = (const int*)d_in[2];
    const float* w      = (const float*)d_in[3];
    const float* Ws     = (const float*)d_in[6];
    const float* W1     = (const float*)d_in[7];
    const float* W2     = (const float*)d_in[8];
    const float* gamma  = (const float*)d_in[9];
    const float* beta   = (const float*)d_in[10];

    const int n_nodes  = in_sizes[0] / D_FEAT;
    const int n_edges  = in_sizes[3];
    const int n_graphs = in_sizes[5];
    const int npg      = n_nodes / n_graphs;

    // workspace layout
    char* ws = (char*)d_ws;
    size_t hBytes    = (size_t)n_nodes * D_FEAT * sizeof(float);       // 25.6 MB
    size_t recBytes  = (size_t)n_edges * sizeof(int2);                 // 9.6 MB
    size_t rsBytes   = (size_t)(n_nodes + 1) * sizeof(int);
    size_t curBytes  = (size_t)n_nodes * sizeof(int);
    size_t partBytes = 256 * sizeof(int);
    size_t need = hBytes + recBytes + rsBytes + curBytes + partBytes;

    float* h = (float*)ws;
    float* agg = (float*)d_out;

    mlp_kernel<<<(n_nodes + 63) / 64, 256, 0, stream>>>(x, states, Ws, W1, W2, h, n_nodes);

    if (ws_size >= need) {
        int2* rec      = (int2*)(ws + hBytes);
        int*  row_start= (int*)(ws + hBytes + recBytes);
        int*  cursor   = (int*)(ws + hBytes + recBytes + rsBytes);
        int*  partials = (int*)(ws + hBytes + recBytes + rsBytes + curBytes);
        int*  counts   = cursor;   // reuse: counts consumed by scan before cursor written

        hipMemsetAsync(counts, 0, (size_t)n_nodes * sizeof(int), stream);
        hist_kernel<<<1024, 256, 0, stream>>>(eidx, counts, n_edges);

        int nchunks = (n_nodes + SCAN_CHUNK - 1) / SCAN_CHUNK;   // 49 for 100k
        scan1_kernel<<<nchunks, 256, 0, stream>>>(counts, row_start, partials, n_nodes);
        scan2_kernel<<<1, 256, 0, stream>>>(partials, nchunks);
        scan3_kernel<<<256, 256, 0, stream>>>(row_start, cursor, partials, n_nodes, n_edges);

        scatter_build_kernel<<<1024, 256, 0, stream>>>(eidx, w, cursor, rec, n_edges);

        gather_kernel<<<(n_nodes + 3) / 4, 256, 0, stream>>>(row_start, rec, h, agg, n_nodes);
    } else {
        hipMemsetAsync(agg, 0, hBytes, stream);
        long long sthreads = (long long)n_edges * 16;
        int sblocks = (int)((sthreads + 255) / 256);
        scatter_atomic_kernel<<<sblocks, 256, 0, stream>>>(eidx, w, h, agg, n_edges);
    }

    norm_kernel<<<n_graphs, 256, 0, stream>>>(agg, gamma, beta, npg);
}